// Round 1
// baseline (51.584 us; speedup 1.0000x reference)
//
#include <hip/hip_runtime.h>

#define BB 2
#define NN 768
#define FIN 10

// workspace layout (float offsets)
#define OFF0_OFF 0                         // B*128
#define S1_OFF   256                       // B*128 (atomic colsum of h1)
#define S2_OFF   512                       // B*128 (atomic colsum of h2)
#define H1_OFF   1024                      // B*128*768
#define H2_OFF   (H1_OFF + BB*128*NN)
#define U_OFF    (H2_OFF + BB*128*NN)
#define PP_OFF   (U_OFF + BB*64*NN)
#define QQ_OFF   (PP_OFF + BB*64*NN)

// ---------------- K1: mean of x over N, then off0[b][o] = b1+b2 - w2 @ mu ----------------
__global__ void k_meanx_off0(const float* __restrict__ x, const float* __restrict__ w2,
                             const float* __restrict__ b1, const float* __restrict__ b2,
                             float* __restrict__ off0)
{
    const int b = blockIdx.x, tid = threadIdx.x;
    __shared__ float red[FIN][256];
    __shared__ float mu[FIN];
    float acc[FIN];
#pragma unroll
    for (int c = 0; c < FIN; ++c) acc[c] = 0.f;
    for (int n = tid; n < NN; n += 256) {
        const float* xp = x + (b * NN + n) * FIN;
#pragma unroll
        for (int c = 0; c < FIN; ++c) acc[c] += xp[c];
    }
#pragma unroll
    for (int c = 0; c < FIN; ++c) red[c][tid] = acc[c];
    __syncthreads();
    for (int s = 128; s > 0; s >>= 1) {
        if (tid < s) {
#pragma unroll
            for (int c = 0; c < FIN; ++c) red[c][tid] += red[c][tid + s];
        }
        __syncthreads();
    }
    if (tid < FIN) mu[tid] = red[tid][0] * (1.f / (float)NN);
    __syncthreads();
    if (tid < 128) {
        float o = b1[tid] + b2[tid];
#pragma unroll
        for (int c = 0; c < FIN; ++c) o -= w2[tid * FIN + c] * mu[c];
        off0[b * 128 + tid] = o;
    }
}

// ---------------- K2: layer0  h1 = relu((w1+w2) @ x^T + off0), colsum -> s1 ----------------
// grid (B, 768/128, 128/32), block 256
__global__ void k_layer0(const float* __restrict__ x, const float* __restrict__ w1,
                         const float* __restrict__ w2, const float* __restrict__ off0,
                         float* __restrict__ h1, float* __restrict__ s1)
{
    const int b = blockIdx.x, n0 = blockIdx.y * 128, o0 = blockIdx.z * 32, tid = threadIdx.x;
    __shared__ alignas(16) float xt[FIN][128];
    __shared__ alignas(16) float wl[FIN][36];
    __shared__ float offs[32];
    __shared__ float red[8][4][33];
    for (int idx = tid; idx < FIN * 128; idx += 256) {
        int nn = idx / FIN, c = idx % FIN;
        xt[c][nn] = x[(b * NN + n0 + nn) * FIN + c];
    }
    for (int idx = tid; idx < 32 * FIN; idx += 256) {
        int o = idx / FIN, c = idx % FIN;
        wl[c][o] = w1[(o0 + o) * FIN + c] + w2[(o0 + o) * FIN + c];
    }
    if (tid < 32) offs[tid] = off0[b * 128 + o0 + tid];
    __syncthreads();
    const int tx = tid & 31, ty = tid >> 5;
    float4 acc[4];
#pragma unroll
    for (int a = 0; a < 4; ++a) {
        float o = offs[ty * 4 + a];
        acc[a] = make_float4(o, o, o, o);
    }
#pragma unroll
    for (int c = 0; c < FIN; ++c) {
        float4 xv = *reinterpret_cast<const float4*>(&xt[c][tx * 4]);
        float4 wv = *reinterpret_cast<const float4*>(&wl[c][ty * 4]);
        float wa[4] = {wv.x, wv.y, wv.z, wv.w};
#pragma unroll
        for (int a = 0; a < 4; ++a) {
            acc[a].x += wa[a] * xv.x;
            acc[a].y += wa[a] * xv.y;
            acc[a].z += wa[a] * xv.z;
            acc[a].w += wa[a] * xv.w;
        }
    }
#pragma unroll
    for (int a = 0; a < 4; ++a) {
        float4 r;
        r.x = fmaxf(acc[a].x, 0.f);
        r.y = fmaxf(acc[a].y, 0.f);
        r.z = fmaxf(acc[a].z, 0.f);
        r.w = fmaxf(acc[a].w, 0.f);
        *reinterpret_cast<float4*>(&h1[((size_t)(b * 128 + o0 + ty * 4 + a)) * NN + n0 + tx * 4]) = r;
        red[ty][a][tx] = r.x + r.y + r.z + r.w;
    }
    __syncthreads();
    if (tid < 32) {
        float s = 0.f;
#pragma unroll
        for (int t = 0; t < 32; ++t) s += red[tid >> 2][tid & 3][t];
        atomicAdd(&s1[b * 128 + o0 + tid], s);
    }
}

// ---------------- K3/K4: generic layer, CIN=128 ----------------
// grid (B, 768/64, COUT/32), block 256
template <int COUT, bool RELU, bool COLSUM>
__global__ void k_layer(const float* __restrict__ hin, const float* __restrict__ w1,
                        const float* __restrict__ b1, const float* __restrict__ b2,
                        const float* __restrict__ w2, const float* __restrict__ csum,
                        float* __restrict__ hout, float* __restrict__ sout)
{
    const int b = blockIdx.x, n0 = blockIdx.y * 64, o0 = blockIdx.z * 32, tid = threadIdx.x;
    __shared__ alignas(16) float hl[128][64];
    __shared__ float wl[128][37];
    __shared__ float mul[128];
    __shared__ float offp[32][9];
    __shared__ float red[16][2][17];
    for (int idx = tid; idx < 128 * 64; idx += 256) {
        int c = idx >> 6, nn = idx & 63;
        hl[c][nn] = hin[((size_t)(b * 128 + c)) * NN + n0 + nn];
    }
    for (int idx = tid; idx < 128 * 32; idx += 256) {
        int o = idx >> 7, c = idx & 127;
        wl[c][o] = w1[(o0 + o) * 128 + c] + w2[(o0 + o) * 128 + c];
    }
    if (tid < 128) mul[tid] = csum[b * 128 + tid] * (1.f / (float)NN);
    __syncthreads();
    // off partials: 8 threads per output channel, 16 c each
    {
        int o = tid >> 3, part = tid & 7;
        float p = 0.f;
        const float* w2r = w2 + (o0 + o) * 128 + part * 16;
        const float* mr = mul + part * 16;
#pragma unroll
        for (int i = 0; i < 16; ++i) p += w2r[i] * mr[i];
        offp[o][part] = p;
    }
    const int tx = tid & 15, ty = tid >> 4;
    float4 acc0 = {0, 0, 0, 0}, acc1 = {0, 0, 0, 0};
#pragma unroll 8
    for (int c = 0; c < 128; ++c) {
        float4 hv = *reinterpret_cast<const float4*>(&hl[c][tx * 4]);
        float w0 = wl[c][ty * 2], w1v = wl[c][ty * 2 + 1];
        acc0.x += w0 * hv.x;
        acc0.y += w0 * hv.y;
        acc0.z += w0 * hv.z;
        acc0.w += w0 * hv.w;
        acc1.x += w1v * hv.x;
        acc1.y += w1v * hv.y;
        acc1.z += w1v * hv.z;
        acc1.w += w1v * hv.w;
    }
    __syncthreads();
#pragma unroll
    for (int a = 0; a < 2; ++a) {
        int o = ty * 2 + a;
        float off = b1[o0 + o] + b2[o0 + o];
#pragma unroll
        for (int p = 0; p < 8; ++p) off -= offp[o][p];
        float4 r = a ? acc1 : acc0;
        r.x += off; r.y += off; r.z += off; r.w += off;
        if (RELU) {
            r.x = fmaxf(r.x, 0.f);
            r.y = fmaxf(r.y, 0.f);
            r.z = fmaxf(r.z, 0.f);
            r.w = fmaxf(r.w, 0.f);
        }
        *reinterpret_cast<float4*>(&hout[((size_t)(b * COUT + o0 + o)) * NN + n0 + tx * 4]) = r;
        if (COLSUM) red[ty][a][tx] = r.x + r.y + r.z + r.w;
    }
    if (COLSUM) {
        __syncthreads();
        if (tid < 32) {
            float s = 0.f;
#pragma unroll
            for (int t = 0; t < 16; ++t) s += red[tid >> 1][tid & 1][t];
            atomicAdd(&sout[b * 128 + o0 + tid], s);
        }
    }
}

// ---------------- K5: pp = sw0[:, :64] @ u + sb0 ; qq = sw0[:, 64:] @ u ----------------
// grid (B, 768/64, 128/32), block 256; virtual channel 0..127: <64 -> pp, >=64 -> qq
__global__ void k_pq(const float* __restrict__ u, const float* __restrict__ sw0,
                     const float* __restrict__ sb0, float* __restrict__ pp,
                     float* __restrict__ qq)
{
    const int b = blockIdx.x, n0 = blockIdx.y * 64, ch0 = blockIdx.z * 32, tid = threadIdx.x;
    __shared__ alignas(16) float ul[64][64];
    __shared__ float wl[64][37];
    __shared__ float bs[32];
    for (int idx = tid; idx < 64 * 64; idx += 256) {
        int c = idx >> 6, nn = idx & 63;
        ul[c][nn] = u[((size_t)(b * 64 + c)) * NN + n0 + nn];
    }
    for (int idx = tid; idx < 64 * 32; idx += 256) {
        int o = idx >> 6, c = idx & 63;
        int ch = ch0 + o;
        wl[c][o] = (ch < 64) ? sw0[ch * 128 + c] : sw0[(ch - 64) * 128 + 64 + c];
    }
    if (tid < 32) {
        int ch = ch0 + tid;
        bs[tid] = (ch < 64) ? sb0[ch] : 0.f;
    }
    __syncthreads();
    const int tx = tid & 15, ty = tid >> 4;
    float b0 = bs[ty * 2], b1v = bs[ty * 2 + 1];
    float4 acc0 = {b0, b0, b0, b0}, acc1 = {b1v, b1v, b1v, b1v};
#pragma unroll 8
    for (int c = 0; c < 64; ++c) {
        float4 hv = *reinterpret_cast<const float4*>(&ul[c][tx * 4]);
        float w0 = wl[c][ty * 2], w1v = wl[c][ty * 2 + 1];
        acc0.x += w0 * hv.x;
        acc0.y += w0 * hv.y;
        acc0.z += w0 * hv.z;
        acc0.w += w0 * hv.w;
        acc1.x += w1v * hv.x;
        acc1.y += w1v * hv.y;
        acc1.z += w1v * hv.z;
        acc1.w += w1v * hv.w;
    }
#pragma unroll
    for (int a = 0; a < 2; ++a) {
        int ch = ch0 + ty * 2 + a;
        float4 r = a ? acc1 : acc0;
        float* dst = (ch < 64) ? (pp + ((size_t)(b * 64 + ch)) * NN)
                               : (qq + ((size_t)(b * 64 + ch - 64)) * NN);
        *reinterpret_cast<float4*>(&dst[n0 + tx * 4]) = r;
    }
}

// ---------------- K6: out[b,i,j] = sb1 + sum_c sw1[c]*relu(pp[c,j]+qq[c,i]) ----------------
// grid (B, 12, 12), block 512; 64x64 output tile, 2i x 4j per thread
__global__ void k_final(const float* __restrict__ pp, const float* __restrict__ qq,
                        const float* __restrict__ sw1, const float* __restrict__ sb1,
                        float* __restrict__ out)
{
    const int b = blockIdx.x, i0 = blockIdx.y * 64, j0 = blockIdx.z * 64, tid = threadIdx.x;
    __shared__ alignas(16) float pl[64][64];
    __shared__ alignas(16) float ql[64][64];
    __shared__ float wl[64];
    __shared__ float sbv;
    for (int idx = tid; idx < 4096; idx += 512) {
        int c = idx >> 6, k = idx & 63;
        pl[c][k] = pp[((size_t)(b * 64 + c)) * NN + j0 + k];
        ql[c][k] = qq[((size_t)(b * 64 + c)) * NN + i0 + k];
    }
    if (tid < 64) wl[tid] = sw1[tid];
    if (tid == 0) sbv = sb1[0];
    __syncthreads();
    const int tx = tid & 15, ty = tid >> 4;  // tx: j/4 (0..15), ty: i/2 (0..31)
    float sb = sbv;
    float4 acc0 = {sb, sb, sb, sb}, acc1 = {sb, sb, sb, sb};
#pragma unroll 8
    for (int c = 0; c < 64; ++c) {
        float4 pv = *reinterpret_cast<const float4*>(&pl[c][tx * 4]);
        float q0 = ql[c][ty * 2], q1 = ql[c][ty * 2 + 1];
        float w = wl[c];
        acc0.x += w * fmaxf(pv.x + q0, 0.f);
        acc0.y += w * fmaxf(pv.y + q0, 0.f);
        acc0.z += w * fmaxf(pv.z + q0, 0.f);
        acc0.w += w * fmaxf(pv.w + q0, 0.f);
        acc1.x += w * fmaxf(pv.x + q1, 0.f);
        acc1.y += w * fmaxf(pv.y + q1, 0.f);
        acc1.z += w * fmaxf(pv.z + q1, 0.f);
        acc1.w += w * fmaxf(pv.w + q1, 0.f);
    }
    size_t base = (size_t)b * NN * NN + (size_t)(i0 + ty * 2) * NN + j0 + tx * 4;
    *reinterpret_cast<float4*>(&out[base]) = acc0;
    *reinterpret_cast<float4*>(&out[base + NN]) = acc1;
}

extern "C" void kernel_launch(void* const* d_in, const int* in_sizes, int n_in,
                              void* d_out, int out_size, void* d_ws, size_t ws_size,
                              hipStream_t stream)
{
    const float* x    = (const float*)d_in[0];
    const float* w1_0 = (const float*)d_in[1];
    const float* b1_0 = (const float*)d_in[2];
    const float* w2_0 = (const float*)d_in[3];
    const float* b2_0 = (const float*)d_in[4];
    const float* w1_1 = (const float*)d_in[5];
    const float* b1_1 = (const float*)d_in[6];
    const float* w2_1 = (const float*)d_in[7];
    const float* b2_1 = (const float*)d_in[8];
    const float* w1_2 = (const float*)d_in[9];
    const float* b1_2 = (const float*)d_in[10];
    const float* w2_2 = (const float*)d_in[11];
    const float* b2_2 = (const float*)d_in[12];
    const float* sw0  = (const float*)d_in[13];
    const float* sb0  = (const float*)d_in[14];
    const float* sw1  = (const float*)d_in[15];
    const float* sb1  = (const float*)d_in[16];

    float* ws   = (float*)d_ws;
    float* off0 = ws + OFF0_OFF;
    float* s1   = ws + S1_OFF;
    float* s2   = ws + S2_OFF;
    float* h1   = ws + H1_OFF;
    float* h2   = ws + H2_OFF;
    float* u    = ws + U_OFF;
    float* pp   = ws + PP_OFF;
    float* qq   = ws + QQ_OFF;

    // zero the atomic colsum accumulators (poisoned workspace otherwise)
    (void)hipMemsetAsync(ws + S1_OFF, 0, 512 * sizeof(float), stream);

    k_meanx_off0<<<BB, 256, 0, stream>>>(x, w2_0, b1_0, b2_0, off0);
    k_layer0<<<dim3(BB, 6, 4), 256, 0, stream>>>(x, w1_0, w2_0, off0, h1, s1);
    k_layer<128, true, true><<<dim3(BB, 12, 4), 256, 0, stream>>>(h1, w1_1, b1_1, b2_1, w2_1, s1, h2, s2);
    k_layer<64, false, false><<<dim3(BB, 12, 2), 256, 0, stream>>>(h2, w1_2, b1_2, b2_2, w2_2, s2, u, nullptr);
    k_pq<<<dim3(BB, 12, 4), 256, 0, stream>>>(u, sw0, sb0, pp, qq);
    k_final<<<dim3(BB, 12, 12), 512, 0, stream>>>(pp, qq, sw1, sb1, (float*)d_out);
}